// Round 3
// baseline (605.139 us; speedup 1.0000x reference)
//
#include <hip/hip_runtime.h>

#define IN_C   16
#define OUT_C  16
#define COEF_M 11
#define PLANE4 4096    // 128*128/4 float4s per plane
#define WSIZE  3328
#define I0     2816    // IN_C*OUT_C*COEF_M
#define I1     3072    // I0 + IN_C*OUT_C

typedef float f4 __attribute__((ext_vector_type(4)));

__device__ __forceinline__ f4 ldnt(const f4* p) {
    return __builtin_nontemporal_load(p);   // w stream: zero reuse, bypass caches
}

// grid = 1024 blocks: 128 pixel-groups (256 px) x 8 o-pairs (2 out-channels each).
// block = 256 threads = 4 waves; wave g handles input channels i in {4g..4g+3}.
// Each lane: 4 consecutive pixels (float4). 1024 blocks -> 3-4 blocks/CU resident
// (vs 2 before) for deeper memory-level parallelism.
__global__ __launch_bounds__(256, 3) void kan_kernel(
    const float* __restrict__ x, const float* __restrict__ w,
    float* __restrict__ out)
{
    const int tid = threadIdx.x;
    const int l   = tid & 63;         // lane within wave
    const int g   = tid >> 6;         // i-group / wave id 0..3
    const int pg  = blockIdx.x >> 3;  // pixel-group 0..127
    const int oq  = blockIdx.x & 7;   // o-pair 0..7
    const int o0  = oq * 2;

    const int p4  = pg * 64 + l;      // float4-pixel index 0..8191
    const int b   = p4 >> 12;         // PLANE4 = 2^12; groups never straddle batch
    const int hw4 = p4 & (PLANE4 - 1);

    const f4* wb4 = (const f4*)w + (size_t)b * WSIZE * PLANE4 + hw4;
    const f4* xb4 = (const f4*)x + (size_t)b * IN_C  * PLANE4 + hw4;

    f4 acc[2];
    acc[0] = f4{0.f, 0.f, 0.f, 0.f};
    acc[1] = f4{0.f, 0.f, 0.f, 0.f};

    #pragma unroll
    for (int ii = 0; ii < 4; ++ii) {
        const int i = g * 4 + ii;
        const f4 xv = xb4[(size_t)i * PLANE4];   // shared by 8 o-blocks -> cached load

        // Cox-de Boor K=3, knots t_j = -1.75 + 0.25*j (componentwise over 4 px)
        f4 bp[14];
        #pragma unroll
        for (int j = 0; j < 14; ++j) {
            const float tj  = -1.75f + 0.25f * j;
            const float tj1 = tj + 0.25f;
            f4 v;
            v.x = (xv.x >= tj && xv.x < tj1) ? 1.f : 0.f;
            v.y = (xv.y >= tj && xv.y < tj1) ? 1.f : 0.f;
            v.z = (xv.z >= tj && xv.z < tj1) ? 1.f : 0.f;
            v.w = (xv.w >= tj && xv.w < tj1) ? 1.f : 0.f;
            bp[j] = v;
        }
        #pragma unroll
        for (int p = 1; p <= 3; ++p) {
            const float inv = 4.0f / (float)p;   // 1/(0.25*p)
            #pragma unroll
            for (int j = 0; j < 14 - p; ++j) {
                const float tj = -1.75f + 0.25f * j;
                const float tr = tj + 0.25f * (float)(p + 1);
                bp[j] = ((xv - tj) * inv) * bp[j] + ((tr - xv) * inv) * bp[j + 1];
            }
        }

        f4 sx;
        sx.x = xv.x / (1.f + __expf(-xv.x));
        sx.y = xv.y / (1.f + __expf(-xv.y));
        sx.z = xv.z / (1.f + __expf(-xv.z));
        sx.w = xv.w / (1.f + __expf(-xv.w));

        #pragma unroll
        for (int oo = 0; oo < 2; ++oo) {
            const int o = o0 + oo;
            const f4* c = wb4 + (size_t)(i * (OUT_C * COEF_M) + o * COEF_M) * PLANE4;
            f4 sp = f4{0.f, 0.f, 0.f, 0.f};
            #pragma unroll
            for (int m = 0; m < COEF_M; ++m)
                sp += ldnt(c + (size_t)m * PLANE4) * bp[m];
            const f4 uwv = ldnt(wb4 + (size_t)(I0 + i * OUT_C + o) * PLANE4);
            const f4 rwv = ldnt(wb4 + (size_t)(I1 + i * OUT_C + o) * PLANE4);
            acc[oo] += uwv * sp + rwv * sx;
        }
    }

    // reduce partials across the 4 i-group waves via LDS (pad to 3 f4 / lane)
    __shared__ f4 red[4][64][3];
    red[g][l][0] = acc[0];
    red[g][l][1] = acc[1];
    __syncthreads();

    if (g < 2) {                       // wave g stores output channel o0+g
        f4 s = red[0][l][g] + red[1][l][g] + red[2][l][g] + red[3][l][g];
        f4* out4 = (f4*)out;
        __builtin_nontemporal_store(
            s, out4 + (size_t)b * (OUT_C * PLANE4) + (size_t)(o0 + g) * PLANE4 + hw4);
    }
}

extern "C" void kernel_launch(void* const* d_in, const int* in_sizes, int n_in,
                              void* d_out, int out_size, void* d_ws, size_t ws_size,
                              hipStream_t stream) {
    const float* x = (const float*)d_in[0];   // (2,16,128,128) fp32
    const float* w = (const float*)d_in[1];   // (2,3328,128,128) fp32
    float* out = (float*)d_out;               // (2,16,128,128) fp32

    kan_kernel<<<dim3(1024), dim3(256), 0, stream>>>(x, w, out);
}